// Round 7
// baseline (966.264 us; speedup 1.0000x reference)
//
#include <hip/hip_runtime.h>
#include <cstdint>

#define NN 100000
#define EE 1600000
#define ET (EE + NN)
#define NBUCK 782            // ceil(NN/128), 128 nodes per bucket
#define BCAP 3584            // fixed per-bucket staging capacity (mean ~2176, sd ~47)

typedef unsigned int u32;
typedef unsigned short u16;

__device__ __forceinline__ u16 f2bf(float f) {
    union { float f; u32 i; } v; v.f = f;
    u32 r = v.i + 0x7FFFu + ((v.i >> 16) & 1u);
    return (u16)(r >> 16);
}
__device__ __forceinline__ float bf2f(u32 u) {
    union { u32 i; float f; } v; v.i = u << 16; return v.f;
}
__device__ __forceinline__ void get_edge(const int* __restrict__ ei, int e, int& s, int& d) {
    if (e < EE) { s = ei[e]; d = ei[EE + e]; }
    else { s = e - EE; d = s; }
}
__device__ __forceinline__ float leaky(float x) { return x > 0.f ? x : 0.2f * x; }

// ---------------- GEMM + fused attn epilogue. X is fp32 (layer 1) or bf16 (layers 2/3).
template<int OUTC, bool IN16>
__global__ __launch_bounds__(256) void gemm_kernel(
    const void* __restrict__ Xv, const float* __restrict__ W,
    const float* __restrict__ asw, const float* __restrict__ adw,
    u16* __restrict__ Hout16, float* __restrict__ as_o, float* __restrict__ ad_o)
{
    constexpr int CG = OUTC / 4;
    constexpr int RG = 256 / CG;
    constexpr int TR = 64 / RG;
    __shared__ float Xs[64 * 132];
    __shared__ float Wt[32 * OUTC];

    const int tid = threadIdx.x;
    const int r0 = blockIdx.x * 64;
    if (IN16) {
        const u32* Xg = (const u32*)Xv;
        for (int i = tid; i < 64 * 32; i += 256) {
            int r = i >> 5, k4 = (i & 31);        // 4-channel group
            float f0 = 0.f, f1 = 0.f, f2 = 0.f, f3 = 0.f;
            if (r0 + r < NN) {
                uint2 w = *(const uint2*)(Xg + (size_t)(r0 + r) * 64 + k4 * 2);
                f0 = bf2f(w.x & 0xffffu); f1 = bf2f(w.x >> 16);
                f2 = bf2f(w.y & 0xffffu); f3 = bf2f(w.y >> 16);
            }
            float* xp = &Xs[r * 132 + k4 * 4];
            xp[0] = f0; xp[1] = f1; xp[2] = f2; xp[3] = f3;
        }
    } else {
        const float* Xf = (const float*)Xv;
        for (int i = tid; i < 64 * 32; i += 256) {
            int r = i >> 5, kk = (i & 31) << 2;
            float4 v = make_float4(0.f, 0.f, 0.f, 0.f);
            if (r0 + r < NN) v = *(const float4*)(Xf + (size_t)(r0 + r) * 128 + kk);
            *(float4*)&Xs[r * 132 + kk] = v;
        }
    }
    const int cg = tid % CG;
    const int rg = tid / CG;
    float acc[TR][4];
    #pragma unroll
    for (int r = 0; r < TR; r++)
        #pragma unroll
        for (int j = 0; j < 4; j++) acc[r][j] = 0.f;

    for (int kc = 0; kc < 4; kc++) {
        __syncthreads();
        for (int i = tid; i < 32 * OUTC / 4; i += 256)
            *(float4*)&Wt[i * 4] = *(const float4*)(W + kc * 32 * OUTC + i * 4);
        __syncthreads();
        #pragma unroll
        for (int k0 = 0; k0 < 32; k0 += 4) {
            float4 xv[TR];
            #pragma unroll
            for (int r = 0; r < TR; r++)
                xv[r] = *(const float4*)&Xs[(rg * TR + r) * 132 + kc * 32 + k0];
            #pragma unroll
            for (int j = 0; j < 4; j++) {
                const int c = cg + CG * j;
                float w0 = Wt[(k0 + 0) * OUTC + c];
                float w1 = Wt[(k0 + 1) * OUTC + c];
                float w2 = Wt[(k0 + 2) * OUTC + c];
                float w3 = Wt[(k0 + 3) * OUTC + c];
                #pragma unroll
                for (int r = 0; r < TR; r++)
                    acc[r][j] += xv[r].x * w0 + xv[r].y * w1 + xv[r].z * w2 + xv[r].w * w3;
            }
        }
    }
    #pragma unroll
    for (int r = 0; r < TR; r++) {
        const int row = r0 + rg * TR + r;
        if (row < NN) {
            #pragma unroll
            for (int j = 0; j < 4; j++)
                Hout16[(size_t)row * OUTC + cg + CG * j] = f2bf(acc[r][j]);
        }
    }
    __syncthreads();
    if (OUTC == 128) {
        #pragma unroll
        for (int r = 0; r < TR; r++)
            #pragma unroll
            for (int j = 0; j < 4; j++)
                Xs[(rg * TR + r) * 132 + cg + 32 * j] = acc[r][j];
        __syncthreads();
        const int row = tid >> 2, part = tid & 3;
        const float* hp = &Xs[row * 132 + part * 32];
        const float* aw = asw + part * 32;
        const float* dw = adw + part * 32;
        float s = 0.f, d = 0.f;
        #pragma unroll
        for (int c = 0; c < 32; c++) { float hv = hp[c]; s += hv * aw[c]; d += hv * dw[c]; }
        const int grow = r0 + row;
        if (grow < NN) { as_o[(size_t)grow * 4 + part] = s; ad_o[(size_t)grow * 4 + part] = d; }
    } else {
        #pragma unroll
        for (int r = 0; r < TR; r++)
            #pragma unroll
            for (int j = 0; j < 4; j++)
                Xs[(rg * TR + r) * 36 + cg + 8 * j] = acc[r][j];
        __syncthreads();
        if (tid < 64) {
            const float* hp = &Xs[tid * 36];
            float s = 0.f, d = 0.f;
            #pragma unroll
            for (int c = 0; c < 32; c++) { float hv = hp[c]; s += hv * asw[c]; d += hv * adw[c]; }
            const int grow = r0 + tid;
            if (grow < NN) { as_o[grow] = s; ad_o[grow] = d; }
        }
    }
}

// ---------------- bucketed CSR build (2 kernels + scan; fixed-capacity staging)
__global__ __launch_bounds__(256) void bin_fill_kernel(const int* __restrict__ ei,
    int* __restrict__ gcur, u32* __restrict__ pairs)
{
    __shared__ int hist[NBUCK];
    __shared__ int base[NBUCK];
    const int t = threadIdx.x;
    for (int i = t; i < NBUCK; i += 256) hist[i] = 0;
    __syncthreads();
    const int chunk = (ET + gridDim.x - 1) / gridDim.x;
    const int e0 = blockIdx.x * chunk;
    const int e1 = min(e0 + chunk, ET);
    for (int e = e0 + t; e < e1; e += 256) {
        int s, d; get_edge(ei, e, s, d);
        atomicAdd(&hist[d >> 7], 1);
    }
    __syncthreads();
    for (int i = t; i < NBUCK; i += 256) {
        int c = hist[i];
        base[i] = c ? atomicAdd(&gcur[i], c) : 0;
        hist[i] = 0;
    }
    __syncthreads();
    for (int e = e0 + t; e < e1; e += 256) {
        int s, d; get_edge(ei, e, s, d);
        int b = d >> 7;
        int pos = atomicAdd(&hist[b], 1);
        pairs[(size_t)b * BCAP + base[b] + pos] = ((u32)(d & 127) << 25) | (u32)s;
    }
}

// exclusive scan of bucket counts -> bbase
__global__ __launch_bounds__(1024) void bscan_kernel(const int* __restrict__ bcnt,
    int* __restrict__ bbase, int* __restrict__ rowp)
{
    __shared__ int lds[1024];
    const int t = threadIdx.x;
    int v = (t < NBUCK) ? bcnt[t] : 0;
    lds[t] = v;
    __syncthreads();
    for (int off = 1; off < 1024; off <<= 1) {
        int x = (t >= off) ? lds[t - off] : 0;
        __syncthreads();
        lds[t] += x;
        __syncthreads();
    }
    if (t < NBUCK) bbase[t] = lds[t] - v;
    if (t == 0) { bbase[NBUCK] = ET; rowp[NN] = ET; }
}

__global__ __launch_bounds__(256) void bucket_csr_kernel(const u32* __restrict__ pairs,
    const int* __restrict__ bcnt, const int* __restrict__ bbase,
    int* __restrict__ rowp, int* __restrict__ col)
{
    __shared__ int hist[128], scn[128];
    __shared__ int col_lds[BCAP];
    const int b = blockIdx.x;
    const int cbase = bbase[b];
    const int cnt = bcnt[b];
    const u32* pk0 = pairs + (size_t)b * BCAP;
    const int t = threadIdx.x;
    if (t < 128) hist[t] = 0;
    __syncthreads();
    for (int i = t; i < cnt; i += 256)
        atomicAdd(&hist[pk0[i] >> 25], 1);
    __syncthreads();
    if (t < 128) scn[t] = hist[t];
    __syncthreads();
    for (int off = 1; off < 128; off <<= 1) {
        int x = (t < 128 && t >= off) ? scn[t - off] : 0;
        __syncthreads();
        if (t < 128) scn[t] += x;
        __syncthreads();
    }
    if (t < 128) {
        int ex = scn[t] - hist[t];
        int node = b * 128 + t;
        if (node < NN) rowp[node] = cbase + ex;
        hist[t] = ex;
    }
    __syncthreads();
    for (int i = t; i < cnt; i += 256) {
        u32 pk = pk0[i];
        int pos = atomicAdd(&hist[pk >> 25], 1);
        if (pos < BCAP) col_lds[pos] = pk & 0x1FFFFFFu;
    }
    __syncthreads();
    for (int i = t; i < cnt; i += 256)
        col[cbase + i] = col_lds[i];
}

// ---------------- fused online-softmax aggregation, H=4: one wave per node.
// 32-edge chunks: lane = h*16+sub computes logits for edges j0+sub and j0+16+sub
// of head h; gather is 32-deep explicit pipeline of u32 loads (2 channels/lane).
// Output written bf16-packed (one u32 store/lane) for the next layer's GEMM.
template<bool DOELU>
__global__ __launch_bounds__(256) void agg4_kernel(
    const int* __restrict__ rowp, const int* __restrict__ col,
    const float* __restrict__ as_, const float* __restrict__ ad_,
    const u16* __restrict__ Hb16, const float* __restrict__ bias,
    u16* __restrict__ outp16)
{
    const int lane = threadIdx.x & 63;
    const int node = blockIdx.x * 4 + (threadIdx.x >> 6);
    const int sub = lane & 15;
    const int h = lane >> 4;

    const int start = rowp[node];
    const int end   = rowp[node + 1];
    const float adv = ad_[(size_t)node * 4 + h];
    const char* hbase = (const char*)Hb16 + lane * 4;
    const float2 bv = *(const float2*)(bias + lane * 2);

    float m = -1e30f, den = 0.f, a0 = 0.f, a1 = 0.f;
    for (int j0 = start; j0 < end; j0 += 32) {
        const int j1 = j0 + sub;
        const int j2 = j0 + 16 + sub;
        const bool v1 = (j1 < end), v2 = (j2 < end);
        const int s1 = v1 ? col[j1] : 0;
        const int s2 = v2 ? col[j2] : 0;
        const float lg1 = v1 ? leaky(as_[(size_t)s1 * 4 + h] + adv) : -1e30f;
        const float lg2 = v2 ? leaky(as_[(size_t)s2 * 4 + h] + adv) : -1e30f;
        float cm = fmaxf(lg1, lg2);
        #pragma unroll
        for (int off = 8; off; off >>= 1) cm = fmaxf(cm, __shfl_xor(cm, off));
        const float mnew = fmaxf(m, cm);
        const float sc = __expf(m - mnew);
        a0 *= sc; a1 *= sc; den *= sc; m = mnew;
        const float p1 = v1 ? __expf(lg1 - m) : 0.f;
        const float p2 = v2 ? __expf(lg2 - m) : 0.f;
        float ps = p1 + p2;
        #pragma unroll
        for (int off = 8; off; off >>= 1) ps += __shfl_xor(ps, off);
        den += ps;
        const int so1 = s1 << 8;     // row byte offset (128 ch * 2 B)
        const int so2 = s2 << 8;
        const int cnt = end - j0;
        if (cnt >= 32) {
            int so[32]; float pi[32];
            #pragma unroll
            for (int i = 0; i < 16; i++) {
                so[i]      = __shfl(so1, i);
                so[i + 16] = __shfl(so2, i);
                pi[i]      = __shfl(p1, (h << 4) | i);
                pi[i + 16] = __shfl(p2, (h << 4) | i);
            }
            #pragma unroll
            for (int i = 0; i < 32; i++) {
                u32 w = *(const u32*)(hbase + so[i]);
                a0 += pi[i] * bf2f(w & 0xffffu);
                a1 += pi[i] * bf2f(w >> 16);
            }
        } else {
            for (int i = 0; i < cnt; i++) {
                int so = (i < 16) ? __shfl(so1, i) : __shfl(so2, i - 16);
                float pi = (i < 16) ? __shfl(p1, (h << 4) | i) : __shfl(p2, (h << 4) | (i - 16));
                u32 w = *(const u32*)(hbase + so);
                a0 += pi * bf2f(w & 0xffffu);
                a1 += pi * bf2f(w >> 16);
            }
        }
    }
    const float rden = 1.f / (den + 1e-16f);
    float v0 = a0 * rden + bv.x;
    float v1 = a1 * rden + bv.y;
    if (DOELU) {
        v0 = v0 > 0.f ? v0 : (__expf(v0) - 1.f);
        v1 = v1 > 0.f ? v1 : (__expf(v1) - 1.f);
    }
    u32 pack = (u32)f2bf(v0) | ((u32)f2bf(v1) << 16);
    *(u32*)(outp16 + (size_t)node * 128 + lane * 2) = pack;
}

// ---------------- H=1 (F=32): 32 lanes per node, 32-edge chunks, fp32 output.
__global__ __launch_bounds__(256) void agg1_kernel(
    const int* __restrict__ rowp, const int* __restrict__ col,
    const float* __restrict__ as_, const float* __restrict__ ad_,
    const u16* __restrict__ Hb16, const float* __restrict__ bias,
    float* __restrict__ outp)
{
    const int t = threadIdx.x;
    const int lane = t & 31;
    const int node = blockIdx.x * 8 + (t >> 5);

    const int start = rowp[node];
    const int end   = rowp[node + 1];
    const float adv = ad_[node];
    const char* hbase = (const char*)Hb16 + lane * 2;
    const float bvv = bias[lane];

    float m = -1e30f, den = 0.f, acc = 0.f;
    for (int j0 = start; j0 < end; j0 += 32) {
        const int j = j0 + lane;
        const bool valid = (j < end);
        const int s = valid ? col[j] : 0;
        const float lg = valid ? leaky(as_[s] + adv) : -1e30f;
        float cm = lg;
        #pragma unroll
        for (int off = 16; off; off >>= 1) cm = fmaxf(cm, __shfl_xor(cm, off, 32));
        const float mnew = fmaxf(m, cm);
        const float sc = __expf(m - mnew);
        acc *= sc; den *= sc; m = mnew;
        const float p = valid ? __expf(lg - m) : 0.f;
        float ps = p;
        #pragma unroll
        for (int off = 16; off; off >>= 1) ps += __shfl_xor(ps, off, 32);
        den += ps;
        const int soff = s << 6;
        const int cnt = end - j0;
        if (cnt >= 32) {
            int so[32]; float pi[32];
            #pragma unroll
            for (int i = 0; i < 32; i++) {
                so[i] = __shfl(soff, i, 32);
                pi[i] = __shfl(p, i, 32);
            }
            #pragma unroll
            for (int i = 0; i < 32; i++)
                acc += pi[i] * bf2f((u32)*(const u16*)(hbase + so[i]));
        } else {
            for (int i = 0; i < cnt; i++) {
                int so = __shfl(soff, i, 32);
                float pi = __shfl(p, i, 32);
                acc += pi * bf2f((u32)*(const u16*)(hbase + so));
            }
        }
    }
    outp[(size_t)node * 32 + lane] = acc / (den + 1e-16f) + bvv;
}

extern "C" void kernel_launch(void* const* d_in, const int* in_sizes, int n_in,
                              void* d_out, int out_size, void* d_ws, size_t ws_size,
                              hipStream_t stream)
{
    const float* x   = (const float*)d_in[0];
    const int*   ei  = (const int*)d_in[1];
    const float* W1  = (const float*)d_in[2];
    const float* as1 = (const float*)d_in[3];
    const float* ad1 = (const float*)d_in[4];
    const float* b1  = (const float*)d_in[5];
    const float* W2  = (const float*)d_in[6];
    const float* as2 = (const float*)d_in[7];
    const float* ad2 = (const float*)d_in[8];
    const float* b2  = (const float*)d_in[9];
    const float* W3  = (const float*)d_in[10];
    const float* as3 = (const float*)d_in[11];
    const float* ad3 = (const float*)d_in[12];
    const float* b3  = (const float*)d_in[13];
    float* outp = (float*)d_out;

    char* ws = (char*)d_ws;
    u16*   hb16  = (u16*)(ws);                    // N*128 bf16 = 25.6 MB (gather source)
    u16*   xb16  = (u16*)(ws + 25700000);         // N*128 bf16 = 25.6 MB (layer input)
    u16*   h3b16 = (u16*)(ws + 51400000);         // N*32 bf16 = 6.4 MB
    float* asb   = (float*)(ws + 57900000);       // N*4 f32
    float* adb   = (float*)(ws + 59500000);       // N*4 f32
    int*   rowp  = (int*)(ws + 61100000);         // N+1 ints
    int*   col   = (int*)(ws + 61600000);         // ET ints = 6.8 MB
    u32*   pairs = (u32*)(ws + 68400032);         // NBUCK*BCAP u32 = 11.2 MB
    int*   gcur  = (int*)(ws + 79700000);         // NBUCK ints (counts after fill)
    int*   bbase = (int*)(ws + 79704096);         // NBUCK+1 ints -> ~79.7 MB total

    const dim3 B(256);
    const int gG = (NN + 63) / 64;   // 1563

    // ---------------- bucketed CSR build (shared by all layers)
    hipMemsetAsync(gcur, 0, NBUCK * 4, stream);
    bin_fill_kernel<<<256, B, 0, stream>>>(ei, gcur, pairs);
    bscan_kernel<<<1, dim3(1024), 0, stream>>>(gcur, bbase, rowp);
    bucket_csr_kernel<<<NBUCK, B, 0, stream>>>(pairs, gcur, bbase, rowp, col);

    // ---------------- layer 1 (H=4)
    gemm_kernel<128, false><<<gG, B, 0, stream>>>(x, W1, as1, ad1, hb16, asb, adb);
    agg4_kernel<true><<<NN / 4, B, 0, stream>>>(rowp, col, asb, adb, hb16, b1, xb16);

    // ---------------- layer 2 (H=4)
    gemm_kernel<128, true><<<gG, B, 0, stream>>>(xb16, W2, as2, ad2, hb16, asb, adb);
    agg4_kernel<true><<<NN / 4, B, 0, stream>>>(rowp, col, asb, adb, hb16, b2, xb16);

    // ---------------- layer 3 (H=1, C=32)
    gemm_kernel<32, true><<<gG, B, 0, stream>>>(xb16, W3, as3, ad3, h3b16, asb, adb);
    agg1_kernel<<<NN / 8, B, 0, stream>>>(rowp, col, asb, adb, h3b16, b3, outp);
}

// Round 8
// 554.253 us; speedup vs baseline: 1.7434x; 1.7434x over previous
//
#include <hip/hip_runtime.h>
#include <cstdint>

#define NN 100000
#define EE 1600000
#define ET (EE + NN)
#define NBUCK 782            // ceil(NN/128), 128 nodes per bucket
#define BCAP 3584            // fixed per-bucket staging capacity (mean ~2176, sd ~47)

typedef unsigned int u32;
typedef unsigned short u16;

__device__ __forceinline__ u16 f2bf(float f) {
    union { float f; u32 i; } v; v.f = f;
    u32 r = v.i + 0x7FFFu + ((v.i >> 16) & 1u);
    return (u16)(r >> 16);
}
__device__ __forceinline__ float bf2f(u32 u) {
    union { u32 i; float f; } v; v.i = u << 16; return v.f;
}
__device__ __forceinline__ void get_edge(const int* __restrict__ ei, int e, int& s, int& d) {
    if (e < EE) { s = ei[e]; d = ei[EE + e]; }
    else { s = e - EE; d = s; }
}
__device__ __forceinline__ float leaky(float x) { return x > 0.f ? x : 0.2f * x; }

// ---------------- GEMM + fused attn epilogue. X is fp32 (layer 1) or bf16 (layers 2/3).
template<int OUTC, bool IN16>
__global__ __launch_bounds__(256) void gemm_kernel(
    const void* __restrict__ Xv, const float* __restrict__ W,
    const float* __restrict__ asw, const float* __restrict__ adw,
    u16* __restrict__ Hout16, float* __restrict__ as_o, float* __restrict__ ad_o)
{
    constexpr int CG = OUTC / 4;
    constexpr int RG = 256 / CG;
    constexpr int TR = 64 / RG;
    __shared__ float Xs[64 * 132];
    __shared__ float Wt[32 * OUTC];

    const int tid = threadIdx.x;
    const int r0 = blockIdx.x * 64;
    if (IN16) {
        const u32* Xg = (const u32*)Xv;
        for (int i = tid; i < 64 * 32; i += 256) {
            int r = i >> 5, k4 = (i & 31);
            float f0 = 0.f, f1 = 0.f, f2 = 0.f, f3 = 0.f;
            if (r0 + r < NN) {
                uint2 w = *(const uint2*)(Xg + (size_t)(r0 + r) * 64 + k4 * 2);
                f0 = bf2f(w.x & 0xffffu); f1 = bf2f(w.x >> 16);
                f2 = bf2f(w.y & 0xffffu); f3 = bf2f(w.y >> 16);
            }
            float* xp = &Xs[r * 132 + k4 * 4];
            xp[0] = f0; xp[1] = f1; xp[2] = f2; xp[3] = f3;
        }
    } else {
        const float* Xf = (const float*)Xv;
        for (int i = tid; i < 64 * 32; i += 256) {
            int r = i >> 5, kk = (i & 31) << 2;
            float4 v = make_float4(0.f, 0.f, 0.f, 0.f);
            if (r0 + r < NN) v = *(const float4*)(Xf + (size_t)(r0 + r) * 128 + kk);
            *(float4*)&Xs[r * 132 + kk] = v;
        }
    }
    const int cg = tid % CG;
    const int rg = tid / CG;
    float acc[TR][4];
    #pragma unroll
    for (int r = 0; r < TR; r++)
        #pragma unroll
        for (int j = 0; j < 4; j++) acc[r][j] = 0.f;

    for (int kc = 0; kc < 4; kc++) {
        __syncthreads();
        for (int i = tid; i < 32 * OUTC / 4; i += 256)
            *(float4*)&Wt[i * 4] = *(const float4*)(W + kc * 32 * OUTC + i * 4);
        __syncthreads();
        #pragma unroll
        for (int k0 = 0; k0 < 32; k0 += 4) {
            float4 xv[TR];
            #pragma unroll
            for (int r = 0; r < TR; r++)
                xv[r] = *(const float4*)&Xs[(rg * TR + r) * 132 + kc * 32 + k0];
            #pragma unroll
            for (int j = 0; j < 4; j++) {
                const int c = cg + CG * j;
                float w0 = Wt[(k0 + 0) * OUTC + c];
                float w1 = Wt[(k0 + 1) * OUTC + c];
                float w2 = Wt[(k0 + 2) * OUTC + c];
                float w3 = Wt[(k0 + 3) * OUTC + c];
                #pragma unroll
                for (int r = 0; r < TR; r++)
                    acc[r][j] += xv[r].x * w0 + xv[r].y * w1 + xv[r].z * w2 + xv[r].w * w3;
            }
        }
    }
    #pragma unroll
    for (int r = 0; r < TR; r++) {
        const int row = r0 + rg * TR + r;
        if (row < NN) {
            #pragma unroll
            for (int j = 0; j < 4; j++)
                Hout16[(size_t)row * OUTC + cg + CG * j] = f2bf(acc[r][j]);
        }
    }
    __syncthreads();
    if (OUTC == 128) {
        #pragma unroll
        for (int r = 0; r < TR; r++)
            #pragma unroll
            for (int j = 0; j < 4; j++)
                Xs[(rg * TR + r) * 132 + cg + 32 * j] = acc[r][j];
        __syncthreads();
        const int row = tid >> 2, part = tid & 3;
        const float* hp = &Xs[row * 132 + part * 32];
        const float* aw = asw + part * 32;
        const float* dw = adw + part * 32;
        float s = 0.f, d = 0.f;
        #pragma unroll
        for (int c = 0; c < 32; c++) { float hv = hp[c]; s += hv * aw[c]; d += hv * dw[c]; }
        const int grow = r0 + row;
        if (grow < NN) { as_o[(size_t)grow * 4 + part] = s; ad_o[(size_t)grow * 4 + part] = d; }
    } else {
        #pragma unroll
        for (int r = 0; r < TR; r++)
            #pragma unroll
            for (int j = 0; j < 4; j++)
                Xs[(rg * TR + r) * 36 + cg + 8 * j] = acc[r][j];
        __syncthreads();
        if (tid < 64) {
            const float* hp = &Xs[tid * 36];
            float s = 0.f, d = 0.f;
            #pragma unroll
            for (int c = 0; c < 32; c++) { float hv = hp[c]; s += hv * asw[c]; d += hv * adw[c]; }
            const int grow = r0 + tid;
            if (grow < NN) { as_o[grow] = s; ad_o[grow] = d; }
        }
    }
}

// ---------------- bucketed CSR build (fixed-capacity staging, 2 edge passes total)
__global__ __launch_bounds__(256) void bin_fill_kernel(const int* __restrict__ ei,
    int* __restrict__ gcur, u32* __restrict__ pairs)
{
    __shared__ int hist[NBUCK];
    __shared__ int base[NBUCK];
    const int t = threadIdx.x;
    for (int i = t; i < NBUCK; i += 256) hist[i] = 0;
    __syncthreads();
    const int chunk = (ET + gridDim.x - 1) / gridDim.x;
    const int e0 = blockIdx.x * chunk;
    const int e1 = min(e0 + chunk, ET);
    for (int e = e0 + t; e < e1; e += 256) {
        int s, d; get_edge(ei, e, s, d);
        atomicAdd(&hist[d >> 7], 1);
    }
    __syncthreads();
    for (int i = t; i < NBUCK; i += 256) {
        int c = hist[i];
        base[i] = c ? atomicAdd(&gcur[i], c) : 0;
        hist[i] = 0;
    }
    __syncthreads();
    for (int e = e0 + t; e < e1; e += 256) {
        int s, d; get_edge(ei, e, s, d);
        int b = d >> 7;
        int pos = atomicAdd(&hist[b], 1);
        pairs[(size_t)b * BCAP + base[b] + pos] = ((u32)(d & 127) << 25) | (u32)s;
    }
}

__global__ __launch_bounds__(1024) void bscan_kernel(const int* __restrict__ bcnt,
    int* __restrict__ bbase, int* __restrict__ rowp)
{
    __shared__ int lds[1024];
    const int t = threadIdx.x;
    int v = (t < NBUCK) ? bcnt[t] : 0;
    lds[t] = v;
    __syncthreads();
    for (int off = 1; off < 1024; off <<= 1) {
        int x = (t >= off) ? lds[t - off] : 0;
        __syncthreads();
        lds[t] += x;
        __syncthreads();
    }
    if (t < NBUCK) bbase[t] = lds[t] - v;
    if (t == 0) { bbase[NBUCK] = ET; rowp[NN] = ET; }
}

__global__ __launch_bounds__(256) void bucket_csr_kernel(const u32* __restrict__ pairs,
    const int* __restrict__ bcnt, const int* __restrict__ bbase,
    int* __restrict__ rowp, int* __restrict__ col)
{
    __shared__ int hist[128], scn[128];
    __shared__ int col_lds[BCAP];
    const int b = blockIdx.x;
    const int cbase = bbase[b];
    const int cnt = bcnt[b];
    const u32* pk0 = pairs + (size_t)b * BCAP;
    const int t = threadIdx.x;
    if (t < 128) hist[t] = 0;
    __syncthreads();
    for (int i = t; i < cnt; i += 256)
        atomicAdd(&hist[pk0[i] >> 25], 1);
    __syncthreads();
    if (t < 128) scn[t] = hist[t];
    __syncthreads();
    for (int off = 1; off < 128; off <<= 1) {
        int x = (t < 128 && t >= off) ? scn[t - off] : 0;
        __syncthreads();
        if (t < 128) scn[t] += x;
        __syncthreads();
    }
    if (t < 128) {
        int ex = scn[t] - hist[t];
        int node = b * 128 + t;
        if (node < NN) rowp[node] = cbase + ex;
        hist[t] = ex;
    }
    __syncthreads();
    for (int i = t; i < cnt; i += 256) {
        u32 pk = pk0[i];
        int pos = atomicAdd(&hist[pk >> 25], 1);
        if (pos < BCAP) col_lds[pos] = pk & 0x1FFFFFFu;
    }
    __syncthreads();
    for (int i = t; i < cnt; i += 256)
        col[cbase + i] = col_lds[i];
}

// ---------------- fused online-softmax aggregation, H=4: one wave per node.
// 16-edge chunks, ALWAYS-pipelined gather: invalid lanes pad with (s=0, p=0) so
// the 16-deep load pipeline runs unconditionally (padding loads hit row 0, L1-hot).
template<bool DOELU>
__global__ __launch_bounds__(256) void agg4_kernel(
    const int* __restrict__ rowp, const int* __restrict__ col,
    const float* __restrict__ as_, const float* __restrict__ ad_,
    const u16* __restrict__ Hb16, const float* __restrict__ bias,
    u16* __restrict__ outp16)
{
    const int lane = threadIdx.x & 63;
    const int node = blockIdx.x * 4 + (threadIdx.x >> 6);
    const int sub = lane & 15;
    const int h = lane >> 4;

    const int start = rowp[node];
    const int end   = rowp[node + 1];
    const float adv = ad_[(size_t)node * 4 + h];
    const char* hbase = (const char*)Hb16 + lane * 4;
    const float2 bv = *(const float2*)(bias + lane * 2);

    float m = -1e30f, den = 0.f, a0 = 0.f, a1 = 0.f;
    for (int j0 = start; j0 < end; j0 += 16) {
        const int j = j0 + sub;
        const bool valid = (j < end);
        const int s = valid ? col[j] : 0;
        const float lg = valid ? leaky(as_[(size_t)s * 4 + h] + adv) : -1e30f;
        float cm = lg;
        #pragma unroll
        for (int off = 8; off; off >>= 1) cm = fmaxf(cm, __shfl_xor(cm, off));
        const float mnew = fmaxf(m, cm);
        const float sc = __expf(m - mnew);
        a0 *= sc; a1 *= sc; den *= sc; m = mnew;
        const float p = valid ? __expf(lg - m) : 0.f;
        float ps = p;
        #pragma unroll
        for (int off = 8; off; off >>= 1) ps += __shfl_xor(ps, off);
        den += ps;
        const int soff = s << 8;    // row byte offset (128 ch * 2 B); 0 for padding
        int so[16]; float pi[16];
        #pragma unroll
        for (int i = 0; i < 16; i++) {
            so[i] = __shfl(soff, i);              // lanes 0..15 hold edges j0+0..j0+15
            pi[i] = __shfl(p, (h << 4) | i);      // own head's p (0 for padding)
        }
        #pragma unroll
        for (int i = 0; i < 16; i++) {
            u32 w = *(const u32*)(hbase + so[i]);
            a0 += pi[i] * bf2f(w & 0xffffu);
            a1 += pi[i] * bf2f(w >> 16);
        }
    }
    const float rden = 1.f / (den + 1e-16f);
    float v0 = a0 * rden + bv.x;
    float v1 = a1 * rden + bv.y;
    if (DOELU) {
        v0 = v0 > 0.f ? v0 : (__expf(v0) - 1.f);
        v1 = v1 > 0.f ? v1 : (__expf(v1) - 1.f);
    }
    u32 pack = (u32)f2bf(v0) | ((u32)f2bf(v1) << 16);
    *(u32*)(outp16 + (size_t)node * 128 + lane * 2) = pack;
}

// ---------------- H=1 (F=32): 32 lanes/node, 32-edge chunks, always-pipelined.
__global__ __launch_bounds__(256) void agg1_kernel(
    const int* __restrict__ rowp, const int* __restrict__ col,
    const float* __restrict__ as_, const float* __restrict__ ad_,
    const u16* __restrict__ Hb16, const float* __restrict__ bias,
    float* __restrict__ outp)
{
    const int t = threadIdx.x;
    const int lane = t & 31;
    const int node = blockIdx.x * 8 + (t >> 5);

    const int start = rowp[node];
    const int end   = rowp[node + 1];
    const float adv = ad_[node];
    const char* hbase = (const char*)Hb16 + lane * 2;
    const float bvv = bias[lane];

    float m = -1e30f, den = 0.f, acc = 0.f;
    for (int j0 = start; j0 < end; j0 += 32) {
        const int j = j0 + lane;
        const bool valid = (j < end);
        const int s = valid ? col[j] : 0;
        const float lg = valid ? leaky(as_[s] + adv) : -1e30f;
        float cm = lg;
        #pragma unroll
        for (int off = 16; off; off >>= 1) cm = fmaxf(cm, __shfl_xor(cm, off, 32));
        const float mnew = fmaxf(m, cm);
        const float sc = __expf(m - mnew);
        acc *= sc; den *= sc; m = mnew;
        const float p = valid ? __expf(lg - m) : 0.f;
        float ps = p;
        #pragma unroll
        for (int off = 16; off; off >>= 1) ps += __shfl_xor(ps, off, 32);
        den += ps;
        const int soff = s << 6;    // 0 for padding
        int so[32]; float pi[32];
        #pragma unroll
        for (int i = 0; i < 32; i++) {
            so[i] = __shfl(soff, i, 32);
            pi[i] = __shfl(p, i, 32);
        }
        #pragma unroll
        for (int i = 0; i < 32; i++)
            acc += pi[i] * bf2f((u32)*(const u16*)(hbase + so[i]));
    }
    outp[(size_t)node * 32 + lane] = acc / (den + 1e-16f) + bvv;
}

extern "C" void kernel_launch(void* const* d_in, const int* in_sizes, int n_in,
                              void* d_out, int out_size, void* d_ws, size_t ws_size,
                              hipStream_t stream)
{
    const float* x   = (const float*)d_in[0];
    const int*   ei  = (const int*)d_in[1];
    const float* W1  = (const float*)d_in[2];
    const float* as1 = (const float*)d_in[3];
    const float* ad1 = (const float*)d_in[4];
    const float* b1  = (const float*)d_in[5];
    const float* W2  = (const float*)d_in[6];
    const float* as2 = (const float*)d_in[7];
    const float* ad2 = (const float*)d_in[8];
    const float* b2  = (const float*)d_in[9];
    const float* W3  = (const float*)d_in[10];
    const float* as3 = (const float*)d_in[11];
    const float* ad3 = (const float*)d_in[12];
    const float* b3  = (const float*)d_in[13];
    float* outp = (float*)d_out;

    char* ws = (char*)d_ws;
    u16*   hb16  = (u16*)(ws);                    // N*128 bf16 = 25.6 MB (gather source)
    u16*   xb16  = (u16*)(ws + 25700000);         // N*128 bf16 = 25.6 MB (layer input)
    u16*   h3b16 = (u16*)(ws + 51400000);         // N*32 bf16 = 6.4 MB
    float* asb   = (float*)(ws + 57900000);       // N*4 f32
    float* adb   = (float*)(ws + 59500000);       // N*4 f32
    int*   rowp  = (int*)(ws + 61100000);         // N+1 ints
    int*   col   = (int*)(ws + 61600000);         // ET ints = 6.8 MB
    u32*   pairs = (u32*)(ws + 68400032);         // NBUCK*BCAP u32 = 11.2 MB
    int*   gcur  = (int*)(ws + 79700000);         // NBUCK ints (counts after fill)
    int*   bbase = (int*)(ws + 79704096);         // NBUCK+1 ints -> ~79.7 MB total

    const dim3 B(256);
    const int gG = (NN + 63) / 64;   // 1563

    // ---------------- bucketed CSR build (shared by all layers)
    hipMemsetAsync(gcur, 0, NBUCK * 4, stream);
    bin_fill_kernel<<<256, B, 0, stream>>>(ei, gcur, pairs);
    bscan_kernel<<<1, dim3(1024), 0, stream>>>(gcur, bbase, rowp);
    bucket_csr_kernel<<<NBUCK, B, 0, stream>>>(pairs, gcur, bbase, rowp, col);

    // ---------------- layer 1 (H=4)
    gemm_kernel<128, false><<<gG, B, 0, stream>>>(x, W1, as1, ad1, hb16, asb, adb);
    agg4_kernel<true><<<NN / 4, B, 0, stream>>>(rowp, col, asb, adb, hb16, b1, xb16);

    // ---------------- layer 2 (H=4)
    gemm_kernel<128, true><<<gG, B, 0, stream>>>(xb16, W2, as2, ad2, hb16, asb, adb);
    agg4_kernel<true><<<NN / 4, B, 0, stream>>>(rowp, col, asb, adb, hb16, b2, xb16);

    // ---------------- layer 3 (H=1, C=32)
    gemm_kernel<32, true><<<gG, B, 0, stream>>>(xb16, W3, as3, ad3, h3b16, asb, adb);
    agg1_kernel<<<NN / 8, B, 0, stream>>>(rowp, col, asb, adb, h3b16, b3, outp);
}

// Round 9
// 461.070 us; speedup vs baseline: 2.0957x; 1.2021x over previous
//
#include <hip/hip_runtime.h>
#include <cstdint>

#define NN 100000
#define EE 1600000
#define ET (EE + NN)
#define NBUCK 782            // ceil(NN/128), 128 nodes per bucket
#define BCAP 3584            // fixed per-bucket staging capacity (mean ~2176, sd ~47)

typedef unsigned int u32;
typedef unsigned short u16;
typedef short bf16x8 __attribute__((ext_vector_type(8)));
typedef float f32x4 __attribute__((ext_vector_type(4)));

__device__ __forceinline__ u16 f2bf(float f) {
    union { float f; u32 i; } v; v.f = f;
    u32 r = v.i + 0x7FFFu + ((v.i >> 16) & 1u);
    return (u16)(r >> 16);
}
__device__ __forceinline__ float bf2f(u32 u) {
    union { u32 i; float f; } v; v.i = u << 16; return v.f;
}
__device__ __forceinline__ void get_edge(const int* __restrict__ ei, int e, int& s, int& d) {
    if (e < EE) { s = ei[e]; d = ei[EE + e]; }
    else { s = e - EE; d = s; }
}
__device__ __forceinline__ float leaky(float x) { return x > 0.f ? x : 0.2f * x; }

// ---------------- W prep: fp32 [k][c] -> bf16 transposed [c][k] (one-time, tiny)
__global__ __launch_bounds__(256) void wprep_kernel(
    const float* __restrict__ W1, const float* __restrict__ W2, const float* __restrict__ W3,
    u16* __restrict__ wt1, u16* __restrict__ wt2, u16* __restrict__ wt3)
{
    int i = blockIdx.x * 256 + threadIdx.x;
    if (i < 16384)      { int c = i >> 7, k = i & 127; wt1[i] = f2bf(W1[k * 128 + c]); }
    else if (i < 32768) { int j = i - 16384; int c = j >> 7, k = j & 127; wt2[j] = f2bf(W2[k * 128 + c]); }
    else if (i < 36864) { int j = i - 32768; int c = j >> 7, k = j & 127; wt3[j] = f2bf(W3[k * 32 + c]); }
}

// ---------------- MFMA GEMM + fused attn epilogue.
// Block: 64 rows x OUTC, 256 thr (4 waves). bf16 MFMA 16x16x32, fp32 accumulate.
// Verified layouts: A[m=lane&15][k=q*8+j], B[n=lane&15][k=q*8+j], C/D col=lane&15 row=q*4+reg.
// X staged bf16 (u32-packed, stride 68 u32); Wt (bf16 [c][k]) staged likewise.
// Epilogue: fp32 acc -> LDS -> exact attn dots + packed-bf16 h store.
template<int OUTC, bool IN16>
__global__ __launch_bounds__(256) void gemm_mfma(
    const void* __restrict__ Xv, const u16* __restrict__ Wt16g,
    const float* __restrict__ asw, const float* __restrict__ adw,
    u16* __restrict__ Hout16, float* __restrict__ as_o, float* __restrict__ ad_o)
{
    constexpr int NT = OUTC / 16;                 // N-tiles per wave: 8 or 2
    constexpr int LDSU = (OUTC == 128) ? 13056 : 6528;
    constexpr int HS = (OUTC == 128) ? 132 : 36;  // fp32 epilogue row stride
    __shared__ u32 lds[LDSU];
    u32* wl = lds + 64 * 68;

    const int tid = threadIdx.x;
    const int r0 = blockIdx.x * 64;

    // stage X -> bf16 pairs, rows stride 68 u32
    if (IN16) {
        const u32* Xg = (const u32*)Xv;
        for (int i = tid; i < 64 * 64; i += 256) {
            int r = i >> 6, k2 = i & 63;
            u32 v = 0;
            if (r0 + r < NN) v = Xg[(size_t)(r0 + r) * 64 + k2];
            lds[r * 68 + k2] = v;
        }
    } else {
        const float* Xf = (const float*)Xv;
        for (int i = tid; i < 64 * 64; i += 256) {
            int r = i >> 6, k2 = i & 63;
            u32 v = 0;
            if (r0 + r < NN) {
                float2 f = *(const float2*)(Xf + (size_t)(r0 + r) * 128 + k2 * 2);
                v = (u32)f2bf(f.x) | ((u32)f2bf(f.y) << 16);
            }
            lds[r * 68 + k2] = v;
        }
    }
    // stage Wt (bf16 [c][128]) -> rows stride 68 u32
    {
        const u32* Wg = (const u32*)Wt16g;
        for (int i = tid; i < OUTC * 64; i += 256) {
            int c = i >> 6, k2 = i & 63;
            wl[c * 68 + k2] = Wg[i];
        }
    }
    __syncthreads();

    const int w = tid >> 6, l = tid & 63;
    const int lm = l & 15, q = l >> 4;

    f32x4 acc[NT];
    #pragma unroll
    for (int T = 0; T < NT; T++)
        #pragma unroll
        for (int r = 0; r < 4; r++) acc[T][r] = 0.f;

    #pragma unroll
    for (int kc = 0; kc < 4; kc++) {
        bf16x8 af = *(const bf16x8*)&lds[(16 * w + lm) * 68 + kc * 16 + q * 4];
        #pragma unroll
        for (int T = 0; T < NT; T++) {
            bf16x8 bfr = *(const bf16x8*)&wl[(16 * T + lm) * 68 + kc * 16 + q * 4];
            acc[T] = __builtin_amdgcn_mfma_f32_16x16x32_bf16(af, bfr, acc[T], 0, 0, 0);
        }
    }
    __syncthreads();

    // dump fp32 acc tile to LDS: row = 16w + q*4 + reg, col = 16T + lm
    float* hl = (float*)lds;
    #pragma unroll
    for (int T = 0; T < NT; T++)
        #pragma unroll
        for (int rg = 0; rg < 4; rg++)
            hl[(16 * w + q * 4 + rg) * HS + 16 * T + lm] = acc[T][rg];
    __syncthreads();

    // packed bf16 h store (coalesced u32)
    for (int i = tid; i < 64 * (OUTC / 2); i += 256) {
        int r = i / (OUTC / 2), k2 = i % (OUTC / 2);
        int row = r0 + r;
        if (row < NN) {
            float a = hl[r * HS + k2 * 2];
            float b = hl[r * HS + k2 * 2 + 1];
            ((u32*)Hout16)[(size_t)row * (OUTC / 2) + k2] = (u32)f2bf(a) | ((u32)f2bf(b) << 16);
        }
    }
    // fused attn dots from fp32 h
    if (OUTC == 128) {
        const int row = tid >> 2, part = tid & 3;
        const float* hp = &hl[row * HS + part * 32];
        const float* aw = asw + part * 32;
        const float* dw = adw + part * 32;
        float s = 0.f, d = 0.f;
        #pragma unroll
        for (int c = 0; c < 32; c++) { float hv = hp[c]; s += hv * aw[c]; d += hv * dw[c]; }
        const int grow = r0 + row;
        if (grow < NN) { as_o[(size_t)grow * 4 + part] = s; ad_o[(size_t)grow * 4 + part] = d; }
    } else {
        if (tid < 64) {
            const float* hp = &hl[tid * HS];
            float s = 0.f, d = 0.f;
            #pragma unroll
            for (int c = 0; c < 32; c++) { float hv = hp[c]; s += hv * asw[c]; d += hv * adw[c]; }
            const int grow = r0 + tid;
            if (grow < NN) { as_o[grow] = s; ad_o[grow] = d; }
        }
    }
}

// ---------------- bucketed CSR build (unchanged from round 8)
__global__ __launch_bounds__(256) void bin_fill_kernel(const int* __restrict__ ei,
    int* __restrict__ gcur, u32* __restrict__ pairs)
{
    __shared__ int hist[NBUCK];
    __shared__ int base[NBUCK];
    const int t = threadIdx.x;
    for (int i = t; i < NBUCK; i += 256) hist[i] = 0;
    __syncthreads();
    const int chunk = (ET + gridDim.x - 1) / gridDim.x;
    const int e0 = blockIdx.x * chunk;
    const int e1 = min(e0 + chunk, ET);
    for (int e = e0 + t; e < e1; e += 256) {
        int s, d; get_edge(ei, e, s, d);
        atomicAdd(&hist[d >> 7], 1);
    }
    __syncthreads();
    for (int i = t; i < NBUCK; i += 256) {
        int c = hist[i];
        base[i] = c ? atomicAdd(&gcur[i], c) : 0;
        hist[i] = 0;
    }
    __syncthreads();
    for (int e = e0 + t; e < e1; e += 256) {
        int s, d; get_edge(ei, e, s, d);
        int b = d >> 7;
        int pos = atomicAdd(&hist[b], 1);
        pairs[(size_t)b * BCAP + base[b] + pos] = ((u32)(d & 127) << 25) | (u32)s;
    }
}

__global__ __launch_bounds__(1024) void bscan_kernel(const int* __restrict__ bcnt,
    int* __restrict__ bbase, int* __restrict__ rowp)
{
    __shared__ int lds[1024];
    const int t = threadIdx.x;
    int v = (t < NBUCK) ? bcnt[t] : 0;
    lds[t] = v;
    __syncthreads();
    for (int off = 1; off < 1024; off <<= 1) {
        int x = (t >= off) ? lds[t - off] : 0;
        __syncthreads();
        lds[t] += x;
        __syncthreads();
    }
    if (t < NBUCK) bbase[t] = lds[t] - v;
    if (t == 0) { bbase[NBUCK] = ET; rowp[NN] = ET; }
}

__global__ __launch_bounds__(256) void bucket_csr_kernel(const u32* __restrict__ pairs,
    const int* __restrict__ bcnt, const int* __restrict__ bbase,
    int* __restrict__ rowp, int* __restrict__ col)
{
    __shared__ int hist[128], scn[128];
    __shared__ int col_lds[BCAP];
    const int b = blockIdx.x;
    const int cbase = bbase[b];
    const int cnt = bcnt[b];
    const u32* pk0 = pairs + (size_t)b * BCAP;
    const int t = threadIdx.x;
    if (t < 128) hist[t] = 0;
    __syncthreads();
    for (int i = t; i < cnt; i += 256)
        atomicAdd(&hist[pk0[i] >> 25], 1);
    __syncthreads();
    if (t < 128) scn[t] = hist[t];
    __syncthreads();
    for (int off = 1; off < 128; off <<= 1) {
        int x = (t < 128 && t >= off) ? scn[t - off] : 0;
        __syncthreads();
        if (t < 128) scn[t] += x;
        __syncthreads();
    }
    if (t < 128) {
        int ex = scn[t] - hist[t];
        int node = b * 128 + t;
        if (node < NN) rowp[node] = cbase + ex;
        hist[t] = ex;
    }
    __syncthreads();
    for (int i = t; i < cnt; i += 256) {
        u32 pk = pk0[i];
        int pos = atomicAdd(&hist[pk >> 25], 1);
        if (pos < BCAP) col_lds[pos] = pk & 0x1FFFFFFu;
    }
    __syncthreads();
    for (int i = t; i < cnt; i += 256)
        col[cbase + i] = col_lds[i];
}

// ---------------- fused online-softmax aggregation (unchanged from round 8)
template<bool DOELU>
__global__ __launch_bounds__(256) void agg4_kernel(
    const int* __restrict__ rowp, const int* __restrict__ col,
    const float* __restrict__ as_, const float* __restrict__ ad_,
    const u16* __restrict__ Hb16, const float* __restrict__ bias,
    u16* __restrict__ outp16)
{
    const int lane = threadIdx.x & 63;
    const int node = blockIdx.x * 4 + (threadIdx.x >> 6);
    const int sub = lane & 15;
    const int h = lane >> 4;

    const int start = rowp[node];
    const int end   = rowp[node + 1];
    const float adv = ad_[(size_t)node * 4 + h];
    const char* hbase = (const char*)Hb16 + lane * 4;
    const float2 bv = *(const float2*)(bias + lane * 2);

    float m = -1e30f, den = 0.f, a0 = 0.f, a1 = 0.f;
    for (int j0 = start; j0 < end; j0 += 16) {
        const int j = j0 + sub;
        const bool valid = (j < end);
        const int s = valid ? col[j] : 0;
        const float lg = valid ? leaky(as_[(size_t)s * 4 + h] + adv) : -1e30f;
        float cm = lg;
        #pragma unroll
        for (int off = 8; off; off >>= 1) cm = fmaxf(cm, __shfl_xor(cm, off));
        const float mnew = fmaxf(m, cm);
        const float sc = __expf(m - mnew);
        a0 *= sc; a1 *= sc; den *= sc; m = mnew;
        const float p = valid ? __expf(lg - m) : 0.f;
        float ps = p;
        #pragma unroll
        for (int off = 8; off; off >>= 1) ps += __shfl_xor(ps, off);
        den += ps;
        const int soff = s << 8;
        int so[16]; float pi[16];
        #pragma unroll
        for (int i = 0; i < 16; i++) {
            so[i] = __shfl(soff, i);
            pi[i] = __shfl(p, (h << 4) | i);
        }
        #pragma unroll
        for (int i = 0; i < 16; i++) {
            u32 wv = *(const u32*)(hbase + so[i]);
            a0 += pi[i] * bf2f(wv & 0xffffu);
            a1 += pi[i] * bf2f(wv >> 16);
        }
    }
    const float rden = 1.f / (den + 1e-16f);
    float v0 = a0 * rden + bv.x;
    float v1 = a1 * rden + bv.y;
    if (DOELU) {
        v0 = v0 > 0.f ? v0 : (__expf(v0) - 1.f);
        v1 = v1 > 0.f ? v1 : (__expf(v1) - 1.f);
    }
    u32 pack = (u32)f2bf(v0) | ((u32)f2bf(v1) << 16);
    *(u32*)(outp16 + (size_t)node * 128 + lane * 2) = pack;
}

__global__ __launch_bounds__(256) void agg1_kernel(
    const int* __restrict__ rowp, const int* __restrict__ col,
    const float* __restrict__ as_, const float* __restrict__ ad_,
    const u16* __restrict__ Hb16, const float* __restrict__ bias,
    float* __restrict__ outp)
{
    const int t = threadIdx.x;
    const int lane = t & 31;
    const int node = blockIdx.x * 8 + (t >> 5);

    const int start = rowp[node];
    const int end   = rowp[node + 1];
    const float adv = ad_[node];
    const char* hbase = (const char*)Hb16 + lane * 2;
    const float bvv = bias[lane];

    float m = -1e30f, den = 0.f, acc = 0.f;
    for (int j0 = start; j0 < end; j0 += 32) {
        const int j = j0 + lane;
        const bool valid = (j < end);
        const int s = valid ? col[j] : 0;
        const float lg = valid ? leaky(as_[s] + adv) : -1e30f;
        float cm = lg;
        #pragma unroll
        for (int off = 16; off; off >>= 1) cm = fmaxf(cm, __shfl_xor(cm, off, 32));
        const float mnew = fmaxf(m, cm);
        const float sc = __expf(m - mnew);
        acc *= sc; den *= sc; m = mnew;
        const float p = valid ? __expf(lg - m) : 0.f;
        float ps = p;
        #pragma unroll
        for (int off = 16; off; off >>= 1) ps += __shfl_xor(ps, off, 32);
        den += ps;
        const int soff = s << 6;
        int so[32]; float pi[32];
        #pragma unroll
        for (int i = 0; i < 32; i++) {
            so[i] = __shfl(soff, i, 32);
            pi[i] = __shfl(p, i, 32);
        }
        #pragma unroll
        for (int i = 0; i < 32; i++)
            acc += pi[i] * bf2f((u32)*(const u16*)(hbase + so[i]));
    }
    outp[(size_t)node * 32 + lane] = acc / (den + 1e-16f) + bvv;
}

extern "C" void kernel_launch(void* const* d_in, const int* in_sizes, int n_in,
                              void* d_out, int out_size, void* d_ws, size_t ws_size,
                              hipStream_t stream)
{
    const float* x   = (const float*)d_in[0];
    const int*   ei  = (const int*)d_in[1];
    const float* W1  = (const float*)d_in[2];
    const float* as1 = (const float*)d_in[3];
    const float* ad1 = (const float*)d_in[4];
    const float* b1  = (const float*)d_in[5];
    const float* W2  = (const float*)d_in[6];
    const float* as2 = (const float*)d_in[7];
    const float* ad2 = (const float*)d_in[8];
    const float* b2  = (const float*)d_in[9];
    const float* W3  = (const float*)d_in[10];
    const float* as3 = (const float*)d_in[11];
    const float* ad3 = (const float*)d_in[12];
    const float* b3  = (const float*)d_in[13];
    float* outp = (float*)d_out;

    char* ws = (char*)d_ws;
    u16*   hb16  = (u16*)(ws);                    // N*128 bf16 = 25.6 MB (gather source)
    u16*   xb16  = (u16*)(ws + 25700000);         // N*128 bf16 = 25.6 MB (layer input)
    u16*   h3b16 = (u16*)(ws + 51400000);         // N*32 bf16 = 6.4 MB
    float* asb   = (float*)(ws + 57900000);       // N*4 f32
    float* adb   = (float*)(ws + 59500000);       // N*4 f32
    int*   rowp  = (int*)(ws + 61100000);         // N+1 ints
    int*   col   = (int*)(ws + 61600000);         // ET ints = 6.8 MB
    u32*   pairs = (u32*)(ws + 68400032);         // NBUCK*BCAP u32 = 11.2 MB
    int*   gcur  = (int*)(ws + 79700000);         // NBUCK ints (counts after fill)
    int*   bbase = (int*)(ws + 79704096);         // NBUCK+1 ints
    u16*   wt1   = (u16*)(ws + 79710000);         // 128x128 bf16 = 32 KB
    u16*   wt2   = (u16*)(ws + 79750000);         // 32 KB
    u16*   wt3   = (u16*)(ws + 79790000);         // 32x128 bf16 = 8 KB -> ~79.8 MB total

    const dim3 B(256);
    const int gG = (NN + 63) / 64;   // 1563

    // ---------------- one-time: W transpose+bf16, bucketed CSR build
    wprep_kernel<<<144, B, 0, stream>>>(W1, W2, W3, wt1, wt2, wt3);
    hipMemsetAsync(gcur, 0, NBUCK * 4, stream);
    bin_fill_kernel<<<256, B, 0, stream>>>(ei, gcur, pairs);
    bscan_kernel<<<1, dim3(1024), 0, stream>>>(gcur, bbase, rowp);
    bucket_csr_kernel<<<NBUCK, B, 0, stream>>>(pairs, gcur, bbase, rowp, col);

    // ---------------- layer 1 (H=4)
    gemm_mfma<128, false><<<gG, B, 0, stream>>>(x, wt1, as1, ad1, hb16, asb, adb);
    agg4_kernel<true><<<NN / 4, B, 0, stream>>>(rowp, col, asb, adb, hb16, b1, xb16);

    // ---------------- layer 2 (H=4)
    gemm_mfma<128, true><<<gG, B, 0, stream>>>(xb16, wt2, as2, ad2, hb16, asb, adb);
    agg4_kernel<true><<<NN / 4, B, 0, stream>>>(rowp, col, asb, adb, hb16, b2, xb16);

    // ---------------- layer 3 (H=1, C=32)
    gemm_mfma<32, true><<<gG, B, 0, stream>>>(xb16, wt3, as3, ad3, h3b16, asb, adb);
    agg1_kernel<<<NN / 8, B, 0, stream>>>(rowp, col, asb, adb, h3b16, b3, outp);
}